// Round 21
// baseline (561.826 us; speedup 1.0000x reference)
//
#include <hip/hip_runtime.h>
#include <math.h>

// ---------------- dims (fixed by the problem) ----------------
#define D_IN     1280
#define D_MODEL  512
#define N_LAYER  4
#define D_STATE  16
#define D_CONV   4
#define D_INNER  1024
#define DT_RANK  32
#define BB       8
#define LL       512
#define M_ROWS   (BB*LL)          // 4096
#define NCHUNK   16
#define LC       (LL/NCHUNK)      // 32

typedef short bf16x8 __attribute__((ext_vector_type(8)));
typedef float f32x4  __attribute__((ext_vector_type(4)));

__device__ __forceinline__ ushort f2bf(float f) {
    unsigned u = __float_as_uint(f);
    u = (u + 0x7FFF + ((u >> 16) & 1)) >> 16;   // RNE
    return (ushort)u;
}
__device__ __forceinline__ float bf2f(ushort u) {
    return __uint_as_float((unsigned)u << 16);
}

// ---------------- fused fp32 -> bf16 casts (6 segments, one launch) -----------
__global__ __launch_bounds__(256) void cast6_k(
    const float* __restrict__ s0, ushort* __restrict__ o0, int n0,
    const float* __restrict__ s1, ushort* __restrict__ o1, int n1,
    const float* __restrict__ s2, ushort* __restrict__ o2, int n2,
    const float* __restrict__ s3, ushort* __restrict__ o3, int n3,
    const float* __restrict__ s4, ushort* __restrict__ o4, int n4,
    const float* __restrict__ s5, ushort* __restrict__ o5, int n5)
{
    int i = blockIdx.x * 256 + threadIdx.x;
    const float* s; ushort* o;
    if (i < n0) { s = s0; o = o0; }
    else if ((i -= n0) < n1) { s = s1; o = o1; }
    else if ((i -= n1) < n2) { s = s2; o = o2; }
    else if ((i -= n2) < n3) { s = s3; o = o3; }
    else if ((i -= n3) < n4) { s = s4; o = o4; }
    else if ((i -= n4) < n5) { s = s5; o = o5; }
    else return;
    float4 v = *(const float4*)(s + (size_t)i * 4);
    *(ushort4*)(o + (size_t)i * 4) =
        make_ushort4(f2bf(v.x), f2bf(v.y), f2bf(v.z), f2bf(v.w));
}

// ============ m97-structure GEMM: 128xBN tile, BK=32, global_load_lds =========
// XCD-chunked swizzle: each XCD owns a contiguous 4-M-tile x all-N slab.
template<int BN, int GX, int NDIM, int KDIM, bool BIAS, bool ACCUM, bool OUTBF>
__global__ __launch_bounds__(256) void gemm_gl(
    const ushort* __restrict__ A, const ushort* __restrict__ W,
    const float* __restrict__ bias, void* __restrict__ Cv)
{
    constexpr int BM = 128, BK = 32;
    constexpr int ACH = BM / 16;
    constexpr int TC  = (BM + BN) / 16;
    constexpr int PW  = TC / 4;
    constexpr int HN  = BN / 2;
    constexpr int FN  = BN / 32;
    constexpr int SM_STAGE = (BM + BN) * BK;
    constexpr int SM_C = OUTBF ? BM * (BN + 8) : 0;
    constexpr int SM = (SM_STAGE > SM_C) ? SM_STAGE : SM_C;
    __shared__ ushort smem[SM];
    ushort* lA = smem;
    ushort* lB = smem + BM * BK;
    const int tid = threadIdx.x, lane = tid & 63, wid = tid >> 6;
    const int wr = wid >> 1, wc = wid & 1;
    const int lin = blockIdx.y * GX + blockIdx.x;
    const int xcd = lin & 7;
    const int idx = lin >> 3;
    const int bm = (xcd * 4 + idx / GX) * BM;
    const int bn = (idx % GX) * BN;
    const int l15 = lane & 15, lk = lane >> 4;
    const int srow = lane >> 2, scol = (lane & 3) * 8;

    f32x4 acc[4][FN];
#pragma unroll
    for (int i = 0; i < 4; ++i)
#pragma unroll
        for (int j = 0; j < FN; ++j) acc[i][j] = (f32x4)0.f;

    for (int kk = 0; kk < KDIM; kk += BK) {
#pragma unroll
        for (int i = 0; i < PW; ++i) {
            const int ch = wid * PW + i;
            const ushort* g = (ch < ACH)
                ? A + (size_t)(bm + ch * 16 + srow) * KDIM + kk + scol
                : W + (size_t)(bn + (ch - ACH) * 16 + srow) * KDIM + kk + scol;
            __builtin_amdgcn_global_load_lds(
                (const __attribute__((address_space(1))) void*)g,
                (__attribute__((address_space(3))) void*)(smem + ch * 512), 16, 0, 0);
        }
        __syncthreads();

        bf16x8 af[4], bw[FN];
#pragma unroll
        for (int fm = 0; fm < 4; ++fm)
            af[fm] = *(const bf16x8*)&lA[(wr * 64 + fm * 16 + l15) * BK + lk * 8];
#pragma unroll
        for (int fn = 0; fn < FN; ++fn)
            bw[fn] = *(const bf16x8*)&lB[(wc * HN + fn * 16 + l15) * BK + lk * 8];
#pragma unroll
        for (int fm = 0; fm < 4; ++fm)
#pragma unroll
            for (int fn = 0; fn < FN; ++fn)
                acc[fm][fn] = __builtin_amdgcn_mfma_f32_16x16x32_bf16(
                    af[fm], bw[fn], acc[fm][fn], 0, 0, 0);
        __syncthreads();
    }

    if (OUTBF) {
        ushort* cst = smem;
#pragma unroll
        for (int fm = 0; fm < 4; ++fm) {
#pragma unroll
            for (int fn = 0; fn < FN; ++fn) {
                const int col = wc * HN + fn * 16 + l15;
                const float bv = BIAS ? bias[bn + col] : 0.f;
#pragma unroll
                for (int j = 0; j < 4; ++j) {
                    const int row = wr * 64 + fm * 16 + lk * 4 + j;
                    cst[row * (BN + 8) + col] = f2bf(acc[fm][fn][j] + bv);
                }
            }
        }
        __syncthreads();
        ushort* Cb = (ushort*)Cv;
        constexpr int NV = BM * BN / 8;
#pragma unroll
        for (int k = 0; k < NV / 256; ++k) {
            const int i = k * 256 + tid;
            const int row = i / (BN / 8), c8 = i % (BN / 8);
            *(uint4*)&Cb[(size_t)(bm + row) * NDIM + bn + c8 * 8] =
                *(uint4*)&cst[row * (BN + 8) + c8 * 8];
        }
    } else {
        float* Cf = (float*)Cv;
#pragma unroll
        for (int fm = 0; fm < 4; ++fm) {
#pragma unroll
            for (int fn = 0; fn < FN; ++fn) {
                const int col = bn + wc * HN + fn * 16 + l15;
                const float bv = BIAS ? bias[col] : 0.f;
#pragma unroll
                for (int j = 0; j < 4; ++j) {
                    const int row = bm + wr * 64 + fm * 16 + lk * 4 + j;
                    float r = acc[fm][fn][j] + bv;
                    float* cp = Cf + (size_t)row * NDIM + col;
                    if (ACCUM) r += *cp;
                    *cp = r;
                }
            }
        }
    }
}

// ======= fused mid chain: conv+silu -> xproj (MFMA) -> dt (MFMA) ==============
// One block per 16 rows (256 blocks). Row-local: no cross-block deps.
__global__ __launch_bounds__(256) void mid_k(
    const ushort* __restrict__ xrb,   // [4096][2048] bf16
    const float* __restrict__ cw, const float* __restrict__ cb,
    const ushort* __restrict__ xpw,   // [64][1024] bf16
    const ushort* __restrict__ dtw,   // [1024][32] bf16
    const float* __restrict__ dt_b,
    ushort* __restrict__ xsb,         // out [4096][1024] bf16
    float* __restrict__ dbc,          // out [4096][32] fp32 (B|C)
    ushort* __restrict__ dltS)        // out [4096][1024] bf16
{
    constexpr int RB  = 16;
    constexpr int LXS = 1032;                 // xs row stride (ushorts)
    __shared__ ushort xs[RB * LXS];           // 33 KB; reused as dlt cst
    __shared__ ushort wl[16 * 64 * 32];       // 64 KB xproj_w half (16 k-chunks)
    __shared__ ushort dbcl[RB * 40];          // delta cols 0..31, bf16

    const int tid = threadIdx.x, lane = tid & 63, wid = tid >> 6;
    const int r0 = blockIdx.x * RB;
    const int l15 = lane & 15, lk = lane >> 4;

    // issue async DMA: xproj_w half 0 (k 0..511), subtiled [kc][64][32]
    {
        const int row = tid >> 2, seg = tid & 3;
#pragma unroll
        for (int r = 0; r < 16; ++r) {
            const ushort* g = xpw + row * 1024 + r * 32 + seg * 8;
            __builtin_amdgcn_global_load_lds(
                (const __attribute__((address_space(1))) void*)g,
                (__attribute__((address_space(3))) void*)(wl + r * 2048 + row * 32 + seg * 8),
                16, 0, 0);
        }
    }

    // ---- phase 1: conv + silu, 4 d-cols per thread, rolling over RB rows ----
    {
        const int d0 = tid * 4;
        float4 w[4];
#pragma unroll
        for (int j = 0; j < 4; ++j) w[j] = *(const float4*)(cw + (d0 + j) * 4);
        const float4 bias = *(const float4*)(cb + d0);
        const float bb[4] = {bias.x, bias.y, bias.z, bias.w};
        const int l0 = r0 & (LL - 1);
        const ushort* base = xrb + (size_t)r0 * 2048 + d0;
        float m3[4] = {0.f, 0.f, 0.f, 0.f};
        float m2[4] = {0.f, 0.f, 0.f, 0.f};
        float m1[4] = {0.f, 0.f, 0.f, 0.f};
        if (l0 != 0) {
            ushort4 a = *(const ushort4*)(base - 3 * 2048);
            ushort4 b = *(const ushort4*)(base - 2 * 2048);
            ushort4 c = *(const ushort4*)(base - 1 * 2048);
            m3[0] = bf2f(a.x); m3[1] = bf2f(a.y); m3[2] = bf2f(a.z); m3[3] = bf2f(a.w);
            m2[0] = bf2f(b.x); m2[1] = bf2f(b.y); m2[2] = bf2f(b.z); m2[3] = bf2f(b.w);
            m1[0] = bf2f(c.x); m1[1] = bf2f(c.y); m1[2] = bf2f(c.z); m1[3] = bf2f(c.w);
        }
        for (int i = 0; i < RB; ++i) {
            ushort4 cu = *(const ushort4*)(base + (size_t)i * 2048);
            float cc[4] = {bf2f(cu.x), bf2f(cu.y), bf2f(cu.z), bf2f(cu.w)};
            ushort ov[4];
#pragma unroll
            for (int j = 0; j < 4; ++j) {
                float o = bb[j] + m3[j] * w[j].x + m2[j] * w[j].y
                        + m1[j] * w[j].z + cc[j] * w[j].w;
                o = o / (1.f + __expf(-o));
                ov[j] = f2bf(o);
                m3[j] = m2[j]; m2[j] = m1[j]; m1[j] = cc[j];
            }
            ushort4 o4 = make_ushort4(ov[0], ov[1], ov[2], ov[3]);
            *(ushort4*)&xs[i * LXS + d0] = o4;
            *(ushort4*)(xsb + (size_t)(r0 + i) * 1024 + d0) = o4;
        }
    }
    __syncthreads();   // xs ready; wl half0 drained

    // ---- phase 2: dbc[16][64] = xs @ xproj_w^T (wave w -> cols w*16..+15) ----
    f32x4 accx = (f32x4)0.f;
#pragma unroll
    for (int ks = 0; ks < 16; ++ks) {
        bf16x8 bf = *(const bf16x8*)&wl[ks * 2048 + (wid * 16 + l15) * 32 + lk * 8];
        bf16x8 af = *(const bf16x8*)&xs[l15 * LXS + ks * 32 + lk * 8];
        accx = __builtin_amdgcn_mfma_f32_16x16x32_bf16(af, bf, accx, 0, 0, 0);
    }
    __syncthreads();   // all done reading half0
    {
        const int row = tid >> 2, seg = tid & 3;
#pragma unroll
        for (int r = 0; r < 16; ++r) {
            const ushort* g = xpw + row * 1024 + 512 + r * 32 + seg * 8;
            __builtin_amdgcn_global_load_lds(
                (const __attribute__((address_space(1))) void*)g,
                (__attribute__((address_space(3))) void*)(wl + r * 2048 + row * 32 + seg * 8),
                16, 0, 0);
        }
    }
    __syncthreads();   // half1 drained
#pragma unroll
    for (int ks = 0; ks < 16; ++ks) {
        bf16x8 bf = *(const bf16x8*)&wl[ks * 2048 + (wid * 16 + l15) * 32 + lk * 8];
        bf16x8 af = *(const bf16x8*)&xs[l15 * LXS + 512 + ks * 32 + lk * 8];
        accx = __builtin_amdgcn_mfma_f32_16x16x32_bf16(af, bf, accx, 0, 0, 0);
    }

    // write results: waves 0,1 -> delta (bf16 LDS); waves 2,3 -> B/C (fp32 global)
    if (wid < 2) {
        const int col = wid * 16 + l15;
#pragma unroll
        for (int j = 0; j < 4; ++j)
            dbcl[(lk * 4 + j) * 40 + col] = f2bf(accx[j]);
    } else {
        const int col = wid * 16 + l15 - 32;
#pragma unroll
        for (int j = 0; j < 4; ++j)
            dbc[(size_t)(r0 + lk * 4 + j) * 32 + col] = accx[j];
    }
    __syncthreads();   // dbcl ready; xs free for reuse

    // ---- phase 3: dlt[16][1024] = softplus(dbcl @ dt_w^T + dt_b) -------------
    {
        bf16x8 af = *(const bf16x8*)&dbcl[l15 * 40 + lk * 8];
        ushort* cst = xs;          // [16][LXS]
#pragma unroll
        for (int q = 0; q < 16; ++q) {
            const int nt = wid * 16 + q;
            bf16x8 bf = *(const bf16x8*)(dtw + (size_t)(nt * 16 + l15) * 32 + lk * 8);
            f32x4 a = __builtin_amdgcn_mfma_f32_16x16x32_bf16(af, bf, (f32x4)0.f, 0, 0, 0);
            const int col = nt * 16 + l15;
            const float bv = dt_b[col];
#pragma unroll
            for (int j = 0; j < 4; ++j) {
                float r = a[j] + bv;
                r = (r > 20.f) ? r : log1pf(expf(r));
                cst[(lk * 4 + j) * LXS + col] = f2bf(r);
            }
        }
        __syncthreads();
#pragma unroll
        for (int k = 0; k < 8; ++k) {
            const int i = k * 256 + tid;
            const int row = i >> 7, c8 = i & 127;
            *(uint4*)(dltS + (size_t)(r0 + row) * 1024 + c8 * 8) =
                *(uint4*)&cst[row * LXS + c8 * 8];
        }
    }
}

// ---------------- RMSNorm over last dim D=512 (bf16 out; layer norms) ---------
__global__ __launch_bounds__(256) void rmsnorm_k(
    const float* __restrict__ X, const float* __restrict__ w,
    ushort* __restrict__ Yb)
{
    const int r = blockIdx.x;
    const float* x = X + (size_t)r * D_MODEL;
    float2 v = *(const float2*)(x + threadIdx.x * 2);
    float ss = v.x * v.x + v.y * v.y;
#pragma unroll
    for (int off = 32; off > 0; off >>= 1) ss += __shfl_down(ss, off);
    __shared__ float wsum[4];
    if ((threadIdx.x & 63) == 0) wsum[threadIdx.x >> 6] = ss;
    __syncthreads();
    float tot = wsum[0] + wsum[1] + wsum[2] + wsum[3];
    float rs = rsqrtf(tot * (1.f / D_MODEL) + 1e-5f);
    float2 wv = *(const float2*)(w + threadIdx.x * 2);
    *(ushort2*)(Yb + (size_t)r * D_MODEL + threadIdx.x * 2) =
        make_ushort2(f2bf(v.x * rs * wv.x), f2bf(v.y * rs * wv.y));
}

// ---------------- selective scan, chunk-parallel, LDS-staged ------------------
// B/C read from compact dbc[4096][32] (B cols 0..15, C cols 16..31).
__global__ __launch_bounds__(256) void scan1_k(
    const ushort* __restrict__ dltS, const ushort* __restrict__ xsb,
    const float* __restrict__ dbc, const float* __restrict__ A_log,
    float2* __restrict__ cb)
{
    const int b    = blockIdx.x >> 8;
    const int c    = (blockIdx.x >> 4) & 15;
    const int dblk = blockIdx.x & 15;
    const int d0   = dblk * 64;
    const int tid  = threadIdx.x;
    const int d    = tid >> 2;
    const int j    = tid & 3;

    __shared__ float sd[LC][64];
    __shared__ float sx[LC][64];
    __shared__ float sB[LC][16];

    const int r0 = b * LL + c * LC;
    {
        const int row = tid >> 3;
        const int q8  = (tid & 7) * 8;
        uint4 v1 = *(const uint4*)(dltS + (size_t)(r0 + row) * D_INNER + d0 + q8);
        uint4 v2 = *(const uint4*)(xsb  + (size_t)(r0 + row) * D_INNER + d0 + q8);
        const int qf = tid & 7;
        float4 bc;
        if (qf < 4) bc = *(const float4*)(dbc + (size_t)(r0 + row) * 32 + qf * 4);
        const ushort* p1 = (const ushort*)&v1;
        const ushort* p2 = (const ushort*)&v2;
#pragma unroll
        for (int u = 0; u < 8; ++u) {
            sd[row][q8 + u] = bf2f(p1[u]);
            sx[row][q8 + u] = bf2f(p2[u]);
        }
        if (qf < 4) *(float4*)&sB[row][qf * 4] = bc;
    }
    __syncthreads();

    float A[4];
#pragma unroll
    for (int s = 0; s < 4; ++s) A[s] = -__expf(A_log[(d0 + d) * D_STATE + j * 4 + s]);

    float h[4] = {}, P[4] = {1.f, 1.f, 1.f, 1.f};
#pragma unroll
    for (int l = 0; l < LC; ++l) {
        const float dt = sd[l][d];
        const float dx = dt * sx[l][d];
        const float4 Bv = *(const float4*)&sB[l][j * 4];
        const float e0 = __expf(dt * A[0]);
        const float e1 = __expf(dt * A[1]);
        const float e2 = __expf(dt * A[2]);
        const float e3 = __expf(dt * A[3]);
        P[0] *= e0; h[0] = fmaf(e0, h[0], dx * Bv.x);
        P[1] *= e1; h[1] = fmaf(e1, h[1], dx * Bv.y);
        P[2] *= e2; h[2] = fmaf(e2, h[2], dx * Bv.z);
        P[3] *= e3; h[3] = fmaf(e3, h[3], dx * Bv.w);
    }
    float2* cp = cb + ((size_t)(b * NCHUNK + c) * D_INNER + d0 + d) * D_STATE + j * 4;
#pragma unroll
    for (int s = 0; s < 4; ++s) cp[s] = make_float2(P[s], h[s]);
}

__global__ __launch_bounds__(256) void scan2_k(
    const ushort* __restrict__ dltS, const ushort* __restrict__ xsb,
    const float* __restrict__ dbc, const ushort* __restrict__ xrb,
    const float* __restrict__ A_log, const float* __restrict__ Dp,
    const float2* __restrict__ cb, ushort* __restrict__ yb)
{
    const int b    = blockIdx.x >> 8;
    const int c    = (blockIdx.x >> 4) & 15;
    const int dblk = blockIdx.x & 15;
    const int d0   = dblk * 64;
    const int tid  = threadIdx.x;
    const int d    = tid >> 2;
    const int j    = tid & 3;

    __shared__ float  sd[LC][64];
    __shared__ float  sx[LC][64];
    __shared__ float  sr[LC][64];
    __shared__ float  sB[LC][16];
    __shared__ float  sC[LC][16];
    __shared__ ushort sy[LC][64];

    const int r0 = b * LL + c * LC;
    {
        const int row = tid >> 3;
        const int q8  = (tid & 7) * 8;
        uint4 v1 = *(const uint4*)(dltS + (size_t)(r0 + row) * D_INNER + d0 + q8);
        uint4 v2 = *(const uint4*)(xsb  + (size_t)(r0 + row) * D_INNER + d0 + q8);
        uint4 v3 = *(const uint4*)(xrb  + (size_t)(r0 + row) * 2 * D_INNER + D_INNER + d0 + q8);
        const int qf = tid & 7;
        float4 bc = *(const float4*)(dbc + (size_t)(r0 + row) * 32 + (qf & 3) * 4 + (qf >> 2) * 16);
        const ushort* p1 = (const ushort*)&v1;
        const ushort* p2 = (const ushort*)&v2;
        const ushort* p3 = (const ushort*)&v3;
#pragma unroll
        for (int u = 0; u < 8; ++u) {
            sd[row][q8 + u] = bf2f(p1[u]);
            sx[row][q8 + u] = bf2f(p2[u]);
            sr[row][q8 + u] = bf2f(p3[u]);
        }
        if (qf < 4) *(float4*)&sB[row][qf * 4] = bc;
        else        *(float4*)&sC[row][(qf - 4) * 4] = bc;
    }
    __syncthreads();

    float A[4];
#pragma unroll
    for (int s = 0; s < 4; ++s) A[s] = -__expf(A_log[(d0 + d) * D_STATE + j * 4 + s]);
    const float Dd = Dp[d0 + d];

    float h[4] = {};
    for (int q = 0; q < NCHUNK - 1; ++q) {
        if (q < c) {
            const float2* cp = cb + ((size_t)(b * NCHUNK + q) * D_INNER + d0 + d) * D_STATE + j * 4;
#pragma unroll
            for (int s = 0; s < 4; ++s) {
                float2 v = cp[s];
                h[s] = fmaf(v.x, h[s], v.y);
            }
        }
    }

#pragma unroll
    for (int l = 0; l < LC; ++l) {
        const float dt = sd[l][d];
        const float xv = sx[l][d];
        const float dx = dt * xv;
        const float4 Bv = *(const float4*)&sB[l][j * 4];
        const float4 Cvv = *(const float4*)&sC[l][j * 4];
        const float e0 = __expf(dt * A[0]);
        const float e1 = __expf(dt * A[1]);
        const float e2 = __expf(dt * A[2]);
        const float e3 = __expf(dt * A[3]);
        float p;
        h[0] = fmaf(e0, h[0], dx * Bv.x); p  = h[0] * Cvv.x;
        h[1] = fmaf(e1, h[1], dx * Bv.y); p = fmaf(h[1], Cvv.y, p);
        h[2] = fmaf(e2, h[2], dx * Bv.z); p = fmaf(h[2], Cvv.z, p);
        h[3] = fmaf(e3, h[3], dx * Bv.w); p = fmaf(h[3], Cvv.w, p);
        p += __shfl_xor(p, 1);
        p += __shfl_xor(p, 2);
        if (j == 0) {
            const float rg = sr[l][d];
            const float g = rg / (1.f + __expf(-rg));
            sy[l][d] = f2bf((p + xv * Dd) * g);
        }
    }
    __syncthreads();
    {
        const int row = tid >> 3;
        const int q8  = (tid & 7) * 8;
        uint4 v;
        ushort* pv = (ushort*)&v;
#pragma unroll
        for (int u = 0; u < 8; ++u) pv[u] = sy[row][q8 + u];
        *(uint4*)(yb + (size_t)(r0 + row) * D_INNER + d0 + q8) = v;
    }
}

// ------- fused final rmsnorm + stats phase 1 (h kept in registers) ------------
__global__ __launch_bounds__(512) void fstats1_k(
    const float* __restrict__ h, const float* __restrict__ w,
    float* __restrict__ part)
{
    const int b = blockIdx.x >> 4, s = blockIdx.x & 15;
    const int dm = threadIdx.x;
    const float wn = w[dm];
    const float* p = h + ((size_t)b * LL + s * 32) * D_MODEL + dm;
    float v[32];
#pragma unroll 8
    for (int l = 0; l < 32; ++l) v[l] = p[(size_t)l * D_MODEL];

    __shared__ float red[32][9];
    const int lane = dm & 63, wv = dm >> 6;
#pragma unroll
    for (int l = 0; l < 32; ++l) {
        float ss = v[l] * v[l];
#pragma unroll
        for (int off = 32; off > 0; off >>= 1) ss += __shfl_down(ss, off);
        if (lane == 0) red[l][wv] = ss;
    }
    __syncthreads();
    float su = 0.f, sq = 0.f;
#pragma unroll
    for (int l = 0; l < 32; ++l) {
        float tot = ((red[l][0] + red[l][1]) + (red[l][2] + red[l][3]))
                  + ((red[l][4] + red[l][5]) + (red[l][6] + red[l][7]));
        float rs = rsqrtf(tot * (1.f / D_MODEL) + 1e-5f);
        float m = v[l] * rs * wn;
        su += m; sq += m * m;
    }
    part[(((size_t)b * 16 + s) * 2 + 0) * D_MODEL + dm] = su;
    part[(((size_t)b * 16 + s) * 2 + 1) * D_MODEL + dm] = sq;
}

__global__ __launch_bounds__(512) void stats2_k(
    const float* __restrict__ part, float* __restrict__ out)
{
    const int b = blockIdx.x;
    const int dm = threadIdx.x;
    float su = 0.f, ss = 0.f;
#pragma unroll
    for (int s = 0; s < 16; ++s) {
        su += part[(((size_t)b * 16 + s) * 2 + 0) * D_MODEL + dm];
        ss += part[(((size_t)b * 16 + s) * 2 + 1) * D_MODEL + dm];
    }
    const float mean = su * (1.f / LL);
    const float var = (ss - su * su * (1.f / LL)) * (1.f / (LL - 1));
    out[b * 2 * D_MODEL + dm] = mean;
    out[b * 2 * D_MODEL + D_MODEL + dm] = sqrtf(fmaxf(var, 0.f));
}

// ---------------- host ----------------
extern "C" void kernel_launch(void* const* d_in, const int* in_sizes, int n_in,
                              void* d_out, int out_size, void* d_ws, size_t ws_size,
                              hipStream_t stream) {
    const float* x            = (const float*)d_in[0];
    const float* proj_w       = (const float*)d_in[1];
    const float* proj_b       = (const float*)d_in[2];
    const float* norm_w       = (const float*)d_in[3];
    const float* in_w         = (const float*)d_in[4];
    const float* conv_w       = (const float*)d_in[5];
    const float* conv_b       = (const float*)d_in[6];
    const float* xproj_w      = (const float*)d_in[7];
    const float* dt_w         = (const float*)d_in[8];
    const float* dt_b         = (const float*)d_in[9];
    const float* A_log        = (const float*)d_in[10];
    const float* Dp           = (const float*)d_in[11];
    const float* out_w        = (const float*)d_in[12];
    const float* final_norm_w = (const float*)d_in[13];

    // fp32 region
    float* ws    = (float*)d_ws;
    float* h     = ws;                                  // 4096*512
    float* dpart = h    + (size_t)M_ROWS * D_MODEL;     // stats partials
    float* dbc   = dpart + (size_t)4 * M_ROWS * 64;     // 4096*32 (compact B|C)
    // bf16 region
    ushort* xyb   = (ushort*)(dbc + (size_t)M_ROWS * 32); // 4096*1280 (x, then y)
    ushort* xnb   = xyb   + (size_t)M_ROWS * D_IN;      // 4096*512
    ushort* xrb   = xnb   + (size_t)M_ROWS * D_MODEL;   // 4096*2048
    ushort* xsb   = xrb   + (size_t)M_ROWS * 2 * D_INNER; // 4096*1024
    ushort* dltS  = xsb   + (size_t)M_ROWS * D_INNER;   // 4096*1024
    ushort* pwb   = dltS  + (size_t)M_ROWS * D_INNER;   // 512*1280
    ushort* iwb4  = pwb   + (size_t)D_MODEL * D_IN;     // 4*2048*512
    ushort* owb4  = iwb4  + (size_t)N_LAYER * 2 * D_INNER * D_MODEL; // 4*512*1024
    ushort* xpwb4 = owb4  + (size_t)N_LAYER * D_MODEL * D_INNER;     // 4*64*1024
    ushort* dtwb4 = xpwb4 + (size_t)N_LAYER * 64 * D_INNER;          // 4*1024*32
    float2* cbuf  = (float2*)(dtwb4 + (size_t)N_LAYER * D_INNER * DT_RANK); // 16.8MB

    // ---- one-time casts, single launch ----
    const int n0 = M_ROWS * D_IN / 4;
    const int n1 = D_MODEL * D_IN / 4;
    const int n2 = N_LAYER * 2 * D_INNER * D_MODEL / 4;
    const int n3 = N_LAYER * D_MODEL * D_INNER / 4;
    const int n4 = N_LAYER * 64 * D_INNER / 4;
    const int n5 = N_LAYER * D_INNER * DT_RANK / 4;
    cast6_k<<<(n0 + n1 + n2 + n3 + n4 + n5 + 255) / 256, 256, 0, stream>>>(
        x, xyb, n0, proj_w, pwb, n1, in_w, iwb4, n2,
        out_w, owb4, n3, xproj_w, xpwb4, n4, dt_w, dtwb4, n5);

    // h = x @ proj_w^T + proj_b   (m97 structure, BN=64, XCD swizzle)
    gemm_gl<64, 8, D_MODEL, D_IN, true, false, false>
        <<<dim3(8, M_ROWS / 128), 256, 0, stream>>>(xyb, pwb, proj_b, h);

    for (int i = 0; i < N_LAYER; ++i) {
        const ushort* iwb  = iwb4  + (size_t)i * 2 * D_INNER * D_MODEL;
        const ushort* owb  = owb4  + (size_t)i * D_MODEL * D_INNER;
        const ushort* xpwb = xpwb4 + (size_t)i * 64 * D_INNER;
        const ushort* dtwb = dtwb4 + (size_t)i * D_INNER * DT_RANK;

        rmsnorm_k<<<M_ROWS, 256, 0, stream>>>(h, norm_w + (size_t)i * D_MODEL, xnb);

        // xr(bf16) = xn @ in_w^T   (m97 structure, BN=128, XCD swizzle)
        gemm_gl<128, 16, 2 * D_INNER, D_MODEL, false, false, true>
            <<<dim3(16, M_ROWS / 128), 256, 0, stream>>>(xnb, iwb, nullptr, xrb);

        // fused conv+silu -> xproj -> dt
        mid_k<<<M_ROWS / 16, 256, 0, stream>>>(
            xrb, conv_w + (size_t)i * D_INNER * D_CONV, conv_b + (size_t)i * D_INNER,
            xpwb, dtwb, dt_b + (size_t)i * D_INNER, xsb, dbc, dltS);

        scan1_k<<<BB * NCHUNK * (D_INNER / 64), 256, 0, stream>>>(
            dltS, xsb, dbc, A_log + (size_t)i * D_INNER * D_STATE, cbuf);
        scan2_k<<<BB * NCHUNK * (D_INNER / 64), 256, 0, stream>>>(
            dltS, xsb, dbc, xrb, A_log + (size_t)i * D_INNER * D_STATE,
            Dp + (size_t)i * D_INNER, cbuf, xyb);

        // h += y @ out_w^T   (m97 structure, BN=64, XCD swizzle)
        gemm_gl<64, 8, D_MODEL, D_INNER, false, true, false>
            <<<dim3(8, M_ROWS / 128), 256, 0, stream>>>(xyb, owb, nullptr, h);
    }

    fstats1_k<<<BB * 16, D_MODEL, 0, stream>>>(h, final_norm_w, dpart);
    stats2_k<<<BB, D_MODEL, 0, stream>>>(dpart, (float*)d_out);
}

// Round 22
// 544.620 us; speedup vs baseline: 1.0316x; 1.0316x over previous
//
#include <hip/hip_runtime.h>
#include <math.h>

// ---------------- dims (fixed by the problem) ----------------
#define D_IN     1280
#define D_MODEL  512
#define N_LAYER  4
#define D_STATE  16
#define D_CONV   4
#define D_INNER  1024
#define DT_RANK  32
#define BB       8
#define LL       512
#define M_ROWS   (BB*LL)          // 4096
#define NCHUNK   16
#define LC       (LL/NCHUNK)      // 32

typedef short bf16x8 __attribute__((ext_vector_type(8)));
typedef float f32x4  __attribute__((ext_vector_type(4)));

__device__ __forceinline__ ushort f2bf(float f) {
    unsigned u = __float_as_uint(f);
    u = (u + 0x7FFF + ((u >> 16) & 1)) >> 16;   // RNE
    return (ushort)u;
}
__device__ __forceinline__ float bf2f(ushort u) {
    return __uint_as_float((unsigned)u << 16);
}

// ---------------- fused fp32 -> bf16 casts (6 segments, one launch) -----------
__global__ __launch_bounds__(256) void cast6_k(
    const float* __restrict__ s0, ushort* __restrict__ o0, int n0,
    const float* __restrict__ s1, ushort* __restrict__ o1, int n1,
    const float* __restrict__ s2, ushort* __restrict__ o2, int n2,
    const float* __restrict__ s3, ushort* __restrict__ o3, int n3,
    const float* __restrict__ s4, ushort* __restrict__ o4, int n4,
    const float* __restrict__ s5, ushort* __restrict__ o5, int n5)
{
    int i = blockIdx.x * 256 + threadIdx.x;
    const float* s; ushort* o;
    if (i < n0) { s = s0; o = o0; }
    else if ((i -= n0) < n1) { s = s1; o = o1; }
    else if ((i -= n1) < n2) { s = s2; o = o2; }
    else if ((i -= n2) < n3) { s = s3; o = o3; }
    else if ((i -= n3) < n4) { s = s4; o = o4; }
    else if ((i -= n4) < n5) { s = s5; o = o5; }
    else return;
    float4 v = *(const float4*)(s + (size_t)i * 4);
    *(ushort4*)(o + (size_t)i * 4) =
        make_ushort4(f2bf(v.x), f2bf(v.y), f2bf(v.z), f2bf(v.w));
}

// ---- split-K reduce for dbc: sum 4 partials; also emit delta cols as bf16 ----
__global__ __launch_bounds__(256) void reduce_dbc_k(
    const float* __restrict__ part, float* __restrict__ dbc,
    ushort* __restrict__ dltb)
{
    const int i = blockIdx.x * 256 + threadIdx.x;   // over 4096*64
    const int c = i & 63;
    float s = part[i] + part[i + M_ROWS * 64] + part[i + 2 * M_ROWS * 64]
            + part[i + 3 * M_ROWS * 64];
    dbc[i] = s;
    if (c < 32) dltb[(i >> 6) * 32 + c] = f2bf(s);
}

// ============ m97-structure GEMM: 128xBN tile, BK=32, global_load_lds =========
// XCD-chunked swizzle: each XCD owns a contiguous 4-M-tile x all-N slab.
template<int BN, int GX, int NDIM, int KDIM, bool BIAS, bool ACCUM, bool OUTBF>
__global__ __launch_bounds__(256) void gemm_gl(
    const ushort* __restrict__ A, const ushort* __restrict__ W,
    const float* __restrict__ bias, void* __restrict__ Cv)
{
    constexpr int BM = 128, BK = 32;
    constexpr int ACH = BM / 16;
    constexpr int TC  = (BM + BN) / 16;
    constexpr int PW  = TC / 4;
    constexpr int HN  = BN / 2;
    constexpr int FN  = BN / 32;
    constexpr int SM_STAGE = (BM + BN) * BK;
    constexpr int SM_C = OUTBF ? BM * (BN + 8) : 0;
    constexpr int SM = (SM_STAGE > SM_C) ? SM_STAGE : SM_C;
    __shared__ ushort smem[SM];
    ushort* lA = smem;
    ushort* lB = smem + BM * BK;
    const int tid = threadIdx.x, lane = tid & 63, wid = tid >> 6;
    const int wr = wid >> 1, wc = wid & 1;
    const int lin = blockIdx.y * GX + blockIdx.x;
    const int xcd = lin & 7;
    const int idx = lin >> 3;
    const int bm = (xcd * 4 + idx / GX) * BM;
    const int bn = (idx % GX) * BN;
    const int l15 = lane & 15, lk = lane >> 4;
    const int srow = lane >> 2, scol = (lane & 3) * 8;

    f32x4 acc[4][FN];
#pragma unroll
    for (int i = 0; i < 4; ++i)
#pragma unroll
        for (int j = 0; j < FN; ++j) acc[i][j] = (f32x4)0.f;

    for (int kk = 0; kk < KDIM; kk += BK) {
#pragma unroll
        for (int i = 0; i < PW; ++i) {
            const int ch = wid * PW + i;
            const ushort* g = (ch < ACH)
                ? A + (size_t)(bm + ch * 16 + srow) * KDIM + kk + scol
                : W + (size_t)(bn + (ch - ACH) * 16 + srow) * KDIM + kk + scol;
            __builtin_amdgcn_global_load_lds(
                (const __attribute__((address_space(1))) void*)g,
                (__attribute__((address_space(3))) void*)(smem + ch * 512), 16, 0, 0);
        }
        __syncthreads();

        bf16x8 af[4], bw[FN];
#pragma unroll
        for (int fm = 0; fm < 4; ++fm)
            af[fm] = *(const bf16x8*)&lA[(wr * 64 + fm * 16 + l15) * BK + lk * 8];
#pragma unroll
        for (int fn = 0; fn < FN; ++fn)
            bw[fn] = *(const bf16x8*)&lB[(wc * HN + fn * 16 + l15) * BK + lk * 8];
#pragma unroll
        for (int fm = 0; fm < 4; ++fm)
#pragma unroll
            for (int fn = 0; fn < FN; ++fn)
                acc[fm][fn] = __builtin_amdgcn_mfma_f32_16x16x32_bf16(
                    af[fm], bw[fn], acc[fm][fn], 0, 0, 0);
        __syncthreads();
    }

    if (OUTBF) {
        ushort* cst = smem;
#pragma unroll
        for (int fm = 0; fm < 4; ++fm) {
#pragma unroll
            for (int fn = 0; fn < FN; ++fn) {
                const int col = wc * HN + fn * 16 + l15;
                const float bv = BIAS ? bias[bn + col] : 0.f;
#pragma unroll
                for (int j = 0; j < 4; ++j) {
                    const int row = wr * 64 + fm * 16 + lk * 4 + j;
                    cst[row * (BN + 8) + col] = f2bf(acc[fm][fn][j] + bv);
                }
            }
        }
        __syncthreads();
        ushort* Cb = (ushort*)Cv;
        constexpr int NV = BM * BN / 8;
#pragma unroll
        for (int k = 0; k < NV / 256; ++k) {
            const int i = k * 256 + tid;
            const int row = i / (BN / 8), c8 = i % (BN / 8);
            *(uint4*)&Cb[(size_t)(bm + row) * NDIM + bn + c8 * 8] =
                *(uint4*)&cst[row * (BN + 8) + c8 * 8];
        }
    } else {
        float* Cf = (float*)Cv;
#pragma unroll
        for (int fm = 0; fm < 4; ++fm) {
#pragma unroll
            for (int fn = 0; fn < FN; ++fn) {
                const int col = bn + wc * HN + fn * 16 + l15;
                const float bv = BIAS ? bias[col] : 0.f;
#pragma unroll
                for (int j = 0; j < 4; ++j) {
                    const int row = bm + wr * 64 + fm * 16 + lk * 4 + j;
                    float r = acc[fm][fn][j] + bv;
                    float* cp = Cf + (size_t)row * NDIM + col;
                    if (ACCUM) r += *cp;
                    *cp = r;
                }
            }
        }
    }
}

// ---------------- bf16 MFMA GEMM (reg-staged; small shapes) -------------------
template<int BM, int BN, bool BIAS, bool ACCUM, int ACT, bool OUTBF>
__global__ __launch_bounds__(256) void gemm_bf16(
    const ushort* __restrict__ A, const ushort* __restrict__ W,
    const float* __restrict__ bias, void* __restrict__ Cv,
    int M, int N, int K, int lda, int ldw)
{
    constexpr int BK = 32;
    constexpr int LDA = BK + 8;
    constexpr int WC = (BM == 128) ? 2 : 4;
    constexpr int HN = BN / WC;
    constexpr int FN = HN / 16;
    constexpr int AL = BM / 64;
    constexpr int BL = (BN * 4 + 255) / 256;
    constexpr int SM_G = (BM + BN) * LDA;
    constexpr int SM_C = OUTBF ? BM * (BN + 8) : 0;
    constexpr int SM   = (SM_G > SM_C) ? SM_G : SM_C;
    __shared__ ushort smem[SM];
    ushort* lA = smem;
    ushort* lB = smem + BM * LDA;
    const int tid  = threadIdx.x;
    const int lane = tid & 63;
    const int wid  = tid >> 6;
    const int wr = (BM == 128) ? (wid >> 1) : 0;
    const int wc = (BM == 128) ? (wid & 1) : wid;
    const int bm = blockIdx.y * BM, bn = blockIdx.x * BN;
    const int koff = blockIdx.z * K;
    const size_t cz = (size_t)blockIdx.z * M * N;
    const int l15 = lane & 15, lk = lane >> 4;

    f32x4 acc[4][FN];
#pragma unroll
    for (int i = 0; i < 4; ++i)
#pragma unroll
        for (int j = 0; j < FN; ++j) acc[i][j] = (f32x4)0.f;

    for (int kk = 0; kk < K; kk += BK) {
        uint4 va[AL], vb[BL];
#pragma unroll
        for (int i = 0; i < AL; ++i) {
            int c = i * 256 + tid, row = c >> 2, k0 = (c & 3) * 8;
            va[i] = *(const uint4*)(A + (size_t)(bm + row) * lda + koff + kk + k0);
        }
#pragma unroll
        for (int i = 0; i < BL; ++i) {
            int c = i * 256 + tid;
            if ((BN * 4 % 256 == 0) || c < BN * 4) {
                int row = c >> 2, k0 = (c & 3) * 8;
                vb[i] = *(const uint4*)(W + (size_t)(bn + row) * ldw + koff + kk + k0);
            }
        }
        __syncthreads();
#pragma unroll
        for (int i = 0; i < AL; ++i) {
            int c = i * 256 + tid, row = c >> 2, k0 = (c & 3) * 8;
            *(uint4*)&lA[row * LDA + k0] = va[i];
        }
#pragma unroll
        for (int i = 0; i < BL; ++i) {
            int c = i * 256 + tid;
            if ((BN * 4 % 256 == 0) || c < BN * 4) {
                int row = c >> 2, k0 = (c & 3) * 8;
                *(uint4*)&lB[row * LDA + k0] = vb[i];
            }
        }
        __syncthreads();

        bf16x8 af[4], bw[FN];
#pragma unroll
        for (int fm = 0; fm < 4; ++fm)
            af[fm] = *(const bf16x8*)&lA[(wr * 64 + fm * 16 + l15) * LDA + lk * 8];
#pragma unroll
        for (int fn = 0; fn < FN; ++fn)
            bw[fn] = *(const bf16x8*)&lB[(wc * HN + fn * 16 + l15) * LDA + lk * 8];
#pragma unroll
        for (int fm = 0; fm < 4; ++fm)
#pragma unroll
            for (int fn = 0; fn < FN; ++fn)
                acc[fm][fn] = __builtin_amdgcn_mfma_f32_16x16x32_bf16(
                    af[fm], bw[fn], acc[fm][fn], 0, 0, 0);
    }

    if (OUTBF) {
        __syncthreads();
        ushort* cst = smem;
#pragma unroll
        for (int fm = 0; fm < 4; ++fm) {
#pragma unroll
            for (int fn = 0; fn < FN; ++fn) {
                int col = wc * HN + fn * 16 + l15;
                float bv = BIAS ? bias[bn + col] : 0.f;
#pragma unroll
                for (int j = 0; j < 4; ++j) {
                    int row = wr * 64 + fm * 16 + lk * 4 + j;
                    float r = acc[fm][fn][j] + bv;
                    if (ACT == 1) r = (r > 20.f) ? r : log1pf(expf(r));
                    cst[row * (BN + 8) + col] = f2bf(r);
                }
            }
        }
        __syncthreads();
        ushort* Cb = (ushort*)Cv + cz;
        constexpr int NV = BM * BN / 8;
#pragma unroll
        for (int k = 0; k < NV / 256; ++k) {
            int i = k * 256 + tid;
            int row = i / (BN / 8), c8 = i % (BN / 8);
            uint4 v = *(uint4*)&cst[row * (BN + 8) + c8 * 8];
            *(uint4*)&Cb[(size_t)(bm + row) * N + bn + c8 * 8] = v;
        }
    } else {
        float* Cf = (float*)Cv + cz;
#pragma unroll
        for (int fm = 0; fm < 4; ++fm) {
#pragma unroll
            for (int fn = 0; fn < FN; ++fn) {
                int col = bn + wc * HN + fn * 16 + l15;
                float bv = BIAS ? bias[col] : 0.f;
#pragma unroll
                for (int j = 0; j < 4; ++j) {
                    int row = bm + wr * 64 + fm * 16 + lk * 4 + j;
                    float r = acc[fm][fn][j] + bv;
                    if (ACT == 1) r = (r > 20.f) ? r : log1pf(expf(r));
                    float* cp = Cf + (size_t)row * N + col;
                    if (ACCUM) r += *cp;
                    *cp = r;
                }
            }
        }
    }
}

// ---------------- RMSNorm over last dim D=512 ---------------------------------
template<bool BF16OUT>
__global__ __launch_bounds__(256) void rmsnorm_k(
    const float* __restrict__ X, const float* __restrict__ w,
    float* __restrict__ Yf, ushort* __restrict__ Yb)
{
    const int r = blockIdx.x;
    const float* x = X + (size_t)r * D_MODEL;
    float2 v = *(const float2*)(x + threadIdx.x * 2);
    float ss = v.x * v.x + v.y * v.y;
#pragma unroll
    for (int off = 32; off > 0; off >>= 1) ss += __shfl_down(ss, off);
    __shared__ float wsum[4];
    if ((threadIdx.x & 63) == 0) wsum[threadIdx.x >> 6] = ss;
    __syncthreads();
    float tot = wsum[0] + wsum[1] + wsum[2] + wsum[3];
    float rs = rsqrtf(tot * (1.f / D_MODEL) + 1e-5f);
    float2 wv = *(const float2*)(w + threadIdx.x * 2);
    float a = v.x * rs * wv.x, b = v.y * rs * wv.y;
    if (BF16OUT)
        *(ushort2*)(Yb + (size_t)r * D_MODEL + threadIdx.x * 2) =
            make_ushort2(f2bf(a), f2bf(b));
    else
        *(float2*)(Yf + (size_t)r * D_MODEL + threadIdx.x * 2) = make_float2(a, b);
}

// ------- depthwise causal conv1d, rolling window: 4 timesteps per thread ------
__global__ __launch_bounds__(256) void conv_silu_k(
    const ushort* __restrict__ xrb, const float* __restrict__ cw,
    const float* __restrict__ cb, ushort* __restrict__ xsb)
{
    const int idx = blockIdx.x * 256 + threadIdx.x;
    const int d = idx & (D_INNER - 1);
    const int g = idx >> 10;
    const int r0 = g * 4;
    const int l0 = r0 & (LL - 1);
    const ushort* base = xrb + (size_t)r0 * (2 * D_INNER) + d;
    const float4 w = *(const float4*)(cw + d * 4);
    const float bias = cb[d];

    float xm3 = 0.f, xm2 = 0.f, xm1 = 0.f;
    if (l0 != 0) {
        xm3 = bf2f(base[-3 * 2 * D_INNER]);
        xm2 = bf2f(base[-2 * 2 * D_INNER]);
        xm1 = bf2f(base[-1 * 2 * D_INNER]);
    }
    const float v0 = bf2f(base[0]);
    const float v1 = bf2f(base[1 * 2 * D_INNER]);
    const float v2 = bf2f(base[2 * 2 * D_INNER]);
    const float v3 = bf2f(base[3 * 2 * D_INNER]);

    float o0 = bias + xm3 * w.x + xm2 * w.y + xm1 * w.z + v0 * w.w;
    float o1 = bias + xm2 * w.x + xm1 * w.y + v0 * w.z + v1 * w.w;
    float o2 = bias + xm1 * w.x + v0 * w.y + v1 * w.z + v2 * w.w;
    float o3 = bias + v0 * w.x + v1 * w.y + v2 * w.z + v3 * w.w;
    o0 = o0 / (1.f + __expf(-o0));
    o1 = o1 / (1.f + __expf(-o1));
    o2 = o2 / (1.f + __expf(-o2));
    o3 = o3 / (1.f + __expf(-o3));
    ushort* out = xsb + (size_t)r0 * D_INNER + d;
    out[0] = f2bf(o0);
    out[1 * D_INNER] = f2bf(o1);
    out[2 * D_INNER] = f2bf(o2);
    out[3 * D_INNER] = f2bf(o3);
}

// ---------------- selective scan, chunk-parallel, LDS-staged ------------------
__global__ __launch_bounds__(256) void scan1_k(
    const ushort* __restrict__ dltS, const ushort* __restrict__ xsb,
    const float* __restrict__ dbc, const float* __restrict__ A_log,
    float2* __restrict__ cb)
{
    const int b    = blockIdx.x >> 8;
    const int c    = (blockIdx.x >> 4) & 15;
    const int dblk = blockIdx.x & 15;
    const int d0   = dblk * 64;
    const int tid  = threadIdx.x;
    const int d    = tid >> 2;
    const int j    = tid & 3;

    __shared__ float sd[LC][64];
    __shared__ float sx[LC][64];
    __shared__ float sB[LC][16];

    const int r0 = b * LL + c * LC;
    {
        const int row = tid >> 3;
        const int q8  = (tid & 7) * 8;
        uint4 v1 = *(const uint4*)(dltS + (size_t)(r0 + row) * D_INNER + d0 + q8);
        uint4 v2 = *(const uint4*)(xsb  + (size_t)(r0 + row) * D_INNER + d0 + q8);
        const int qf = tid & 7;
        float4 bc;
        if (qf < 4) bc = *(const float4*)(dbc + (size_t)(r0 + row) * 64 + 32 + qf * 4);
        const ushort* p1 = (const ushort*)&v1;
        const ushort* p2 = (const ushort*)&v2;
#pragma unroll
        for (int u = 0; u < 8; ++u) {
            sd[row][q8 + u] = bf2f(p1[u]);
            sx[row][q8 + u] = bf2f(p2[u]);
        }
        if (qf < 4) *(float4*)&sB[row][qf * 4] = bc;
    }
    __syncthreads();

    float A[4];
#pragma unroll
    for (int s = 0; s < 4; ++s) A[s] = -__expf(A_log[(d0 + d) * D_STATE + j * 4 + s]);

    float h[4] = {}, P[4] = {1.f, 1.f, 1.f, 1.f};
#pragma unroll
    for (int l = 0; l < LC; ++l) {
        const float dt = sd[l][d];
        const float dx = dt * sx[l][d];
        const float4 Bv = *(const float4*)&sB[l][j * 4];
        const float e0 = __expf(dt * A[0]);
        const float e1 = __expf(dt * A[1]);
        const float e2 = __expf(dt * A[2]);
        const float e3 = __expf(dt * A[3]);
        P[0] *= e0; h[0] = fmaf(e0, h[0], dx * Bv.x);
        P[1] *= e1; h[1] = fmaf(e1, h[1], dx * Bv.y);
        P[2] *= e2; h[2] = fmaf(e2, h[2], dx * Bv.z);
        P[3] *= e3; h[3] = fmaf(e3, h[3], dx * Bv.w);
    }
    float2* cp = cb + ((size_t)(b * NCHUNK + c) * D_INNER + d0 + d) * D_STATE + j * 4;
#pragma unroll
    for (int s = 0; s < 4; ++s) cp[s] = make_float2(P[s], h[s]);
}

__global__ __launch_bounds__(256) void scan2_k(
    const ushort* __restrict__ dltS, const ushort* __restrict__ xsb,
    const float* __restrict__ dbc, const ushort* __restrict__ xrb,
    const float* __restrict__ A_log, const float* __restrict__ Dp,
    const float2* __restrict__ cb, ushort* __restrict__ yb)
{
    const int b    = blockIdx.x >> 8;
    const int c    = (blockIdx.x >> 4) & 15;
    const int dblk = blockIdx.x & 15;
    const int d0   = dblk * 64;
    const int tid  = threadIdx.x;
    const int d    = tid >> 2;
    const int j    = tid & 3;

    __shared__ float  sd[LC][64];
    __shared__ float  sx[LC][64];
    __shared__ float  sr[LC][64];
    __shared__ float  sB[LC][16];
    __shared__ float  sC[LC][16];
    __shared__ ushort sy[LC][64];

    const int r0 = b * LL + c * LC;
    {
        const int row = tid >> 3;
        const int q8  = (tid & 7) * 8;
        uint4 v1 = *(const uint4*)(dltS + (size_t)(r0 + row) * D_INNER + d0 + q8);
        uint4 v2 = *(const uint4*)(xsb  + (size_t)(r0 + row) * D_INNER + d0 + q8);
        uint4 v3 = *(const uint4*)(xrb  + (size_t)(r0 + row) * 2 * D_INNER + D_INNER + d0 + q8);
        const int qf = tid & 7;
        float4 bc = *(const float4*)(dbc + (size_t)(r0 + row) * 64 + 32 + qf * 4);
        const ushort* p1 = (const ushort*)&v1;
        const ushort* p2 = (const ushort*)&v2;
        const ushort* p3 = (const ushort*)&v3;
#pragma unroll
        for (int u = 0; u < 8; ++u) {
            sd[row][q8 + u] = bf2f(p1[u]);
            sx[row][q8 + u] = bf2f(p2[u]);
            sr[row][q8 + u] = bf2f(p3[u]);
        }
        if (qf < 4) *(float4*)&sB[row][qf * 4] = bc;
        else        *(float4*)&sC[row][(qf - 4) * 4] = bc;
    }
    __syncthreads();

    float A[4];
#pragma unroll
    for (int s = 0; s < 4; ++s) A[s] = -__expf(A_log[(d0 + d) * D_STATE + j * 4 + s]);
    const float Dd = Dp[d0 + d];

    float h[4] = {};
    for (int q = 0; q < NCHUNK - 1; ++q) {
        if (q < c) {
            const float2* cp = cb + ((size_t)(b * NCHUNK + q) * D_INNER + d0 + d) * D_STATE + j * 4;
#pragma unroll
            for (int s = 0; s < 4; ++s) {
                float2 v = cp[s];
                h[s] = fmaf(v.x, h[s], v.y);
            }
        }
    }

#pragma unroll
    for (int l = 0; l < LC; ++l) {
        const float dt = sd[l][d];
        const float xv = sx[l][d];
        const float dx = dt * xv;
        const float4 Bv = *(const float4*)&sB[l][j * 4];
        const float4 Cvv = *(const float4*)&sC[l][j * 4];
        const float e0 = __expf(dt * A[0]);
        const float e1 = __expf(dt * A[1]);
        const float e2 = __expf(dt * A[2]);
        const float e3 = __expf(dt * A[3]);
        float p;
        h[0] = fmaf(e0, h[0], dx * Bv.x); p  = h[0] * Cvv.x;
        h[1] = fmaf(e1, h[1], dx * Bv.y); p = fmaf(h[1], Cvv.y, p);
        h[2] = fmaf(e2, h[2], dx * Bv.z); p = fmaf(h[2], Cvv.z, p);
        h[3] = fmaf(e3, h[3], dx * Bv.w); p = fmaf(h[3], Cvv.w, p);
        p += __shfl_xor(p, 1);
        p += __shfl_xor(p, 2);
        if (j == 0) {
            const float rg = sr[l][d];
            const float g = rg / (1.f + __expf(-rg));
            sy[l][d] = f2bf((p + xv * Dd) * g);
        }
    }
    __syncthreads();
    {
        const int row = tid >> 3;
        const int q8  = (tid & 7) * 8;
        uint4 v;
        ushort* pv = (ushort*)&v;
#pragma unroll
        for (int u = 0; u < 8; ++u) pv[u] = sy[row][q8 + u];
        *(uint4*)(yb + (size_t)(r0 + row) * D_INNER + d0 + q8) = v;
    }
}

// ---------------- final stats, two-phase ----------------
__global__ __launch_bounds__(512) void stats1_k(
    const float* __restrict__ m, float* __restrict__ part)
{
    const int b = blockIdx.x >> 4, s = blockIdx.x & 15;
    const int dm = threadIdx.x;
    const float* p = m + ((size_t)b * LL + s * 32) * D_MODEL + dm;
    float su = 0.f, ss = 0.f;
#pragma unroll 4
    for (int l = 0; l < 32; ++l) {
        float v = p[(size_t)l * D_MODEL];
        su += v; ss += v * v;
    }
    part[(((size_t)b * 16 + s) * 2 + 0) * D_MODEL + dm] = su;
    part[(((size_t)b * 16 + s) * 2 + 1) * D_MODEL + dm] = ss;
}

__global__ __launch_bounds__(512) void stats2_k(
    const float* __restrict__ part, float* __restrict__ out)
{
    const int b = blockIdx.x;
    const int dm = threadIdx.x;
    float su = 0.f, ss = 0.f;
#pragma unroll
    for (int s = 0; s < 16; ++s) {
        su += part[(((size_t)b * 16 + s) * 2 + 0) * D_MODEL + dm];
        ss += part[(((size_t)b * 16 + s) * 2 + 1) * D_MODEL + dm];
    }
    const float mean = su * (1.f / LL);
    const float var = (ss - su * su * (1.f / LL)) * (1.f / (LL - 1));
    out[b * 2 * D_MODEL + dm] = mean;
    out[b * 2 * D_MODEL + D_MODEL + dm] = sqrtf(fmaxf(var, 0.f));
}

// ---------------- host ----------------
extern "C" void kernel_launch(void* const* d_in, const int* in_sizes, int n_in,
                              void* d_out, int out_size, void* d_ws, size_t ws_size,
                              hipStream_t stream) {
    const float* x            = (const float*)d_in[0];
    const float* proj_w       = (const float*)d_in[1];
    const float* proj_b       = (const float*)d_in[2];
    const float* norm_w       = (const float*)d_in[3];
    const float* in_w         = (const float*)d_in[4];
    const float* conv_w       = (const float*)d_in[5];
    const float* conv_b       = (const float*)d_in[6];
    const float* xproj_w      = (const float*)d_in[7];
    const float* dt_w         = (const float*)d_in[8];
    const float* dt_b         = (const float*)d_in[9];
    const float* A_log        = (const float*)d_in[10];
    const float* Dp           = (const float*)d_in[11];
    const float* out_w        = (const float*)d_in[12];
    const float* final_norm_w = (const float*)d_in[13];

    // fp32 region
    float* ws    = (float*)d_ws;
    float* h     = ws;                                  // 4096*512
    float* dbc   = h    + (size_t)M_ROWS * D_MODEL;     // 4096*64
    float* dpart = dbc  + (size_t)M_ROWS * 64;          // 4*4096*64 (stats reuse)
    // bf16 region
    ushort* xyb   = (ushort*)(dpart + (size_t)4 * M_ROWS * 64); // 4096*1280 (x, then y)
    ushort* xnb   = xyb   + (size_t)M_ROWS * D_IN;      // 4096*512
    ushort* xrb   = xnb   + (size_t)M_ROWS * D_MODEL;   // 4096*2048 (fnorm f32 alias)
    ushort* xsb   = xrb   + (size_t)M_ROWS * 2 * D_INNER; // 4096*1024
    ushort* dltS  = xsb   + (size_t)M_ROWS * D_INNER;   // 4096*1024
    ushort* dltb  = dltS  + (size_t)M_ROWS * D_INNER;   // 4096*32
    ushort* pwb   = dltb  + (size_t)M_ROWS * DT_RANK;   // 512*1280
    ushort* iwb4  = pwb   + (size_t)D_MODEL * D_IN;     // 4*2048*512
    ushort* owb4  = iwb4  + (size_t)N_LAYER * 2 * D_INNER * D_MODEL; // 4*512*1024
    ushort* xpwb4 = owb4  + (size_t)N_LAYER * D_MODEL * D_INNER;     // 4*64*1024
    ushort* dtwb4 = xpwb4 + (size_t)N_LAYER * 64 * D_INNER;          // 4*1024*32
    float2* cbuf  = (float2*)(dtwb4 + (size_t)N_LAYER * D_INNER * DT_RANK); // 16.8MB
    float* fnorm  = (float*)xrb;

    // ---- one-time casts, single launch ----
    const int n0 = M_ROWS * D_IN / 4;
    const int n1 = D_MODEL * D_IN / 4;
    const int n2 = N_LAYER * 2 * D_INNER * D_MODEL / 4;
    const int n3 = N_LAYER * D_MODEL * D_INNER / 4;
    const int n4 = N_LAYER * 64 * D_INNER / 4;
    const int n5 = N_LAYER * D_INNER * DT_RANK / 4;
    cast6_k<<<(n0 + n1 + n2 + n3 + n4 + n5 + 255) / 256, 256, 0, stream>>>(
        x, xyb, n0, proj_w, pwb, n1, in_w, iwb4, n2,
        out_w, owb4, n3, xproj_w, xpwb4, n4, dt_w, dtwb4, n5);

    // h = x @ proj_w^T + proj_b   (m97 structure, BN=64, XCD swizzle)
    gemm_gl<64, 8, D_MODEL, D_IN, true, false, false>
        <<<dim3(8, M_ROWS / 128), 256, 0, stream>>>(xyb, pwb, proj_b, h);

    for (int i = 0; i < N_LAYER; ++i) {
        const ushort* iwb  = iwb4  + (size_t)i * 2 * D_INNER * D_MODEL;
        const ushort* owb  = owb4  + (size_t)i * D_MODEL * D_INNER;
        const ushort* xpwb = xpwb4 + (size_t)i * 64 * D_INNER;
        const ushort* dtwb = dtwb4 + (size_t)i * D_INNER * DT_RANK;

        rmsnorm_k<true><<<M_ROWS, 256, 0, stream>>>(h, norm_w + (size_t)i * D_MODEL, nullptr, xnb);

        // xr(bf16) = xn @ in_w^T   (m97 structure, BN=128, XCD swizzle)
        gemm_gl<128, 16, 2 * D_INNER, D_MODEL, false, false, true>
            <<<dim3(16, M_ROWS / 128), 256, 0, stream>>>(xnb, iwb, nullptr, xrb);

        conv_silu_k<<<M_ROWS * D_INNER / 4 / 256, 256, 0, stream>>>(
            xrb, conv_w + (size_t)i * D_INNER * D_CONV, conv_b + (size_t)i * D_INNER, xsb);

        // dbc partials = xs @ xproj_w^T, split-K=4
        gemm_bf16<128, 32, false, false, 0, false><<<dim3(2, M_ROWS / 128, 4), 256, 0, stream>>>(
            xsb, xpwb, nullptr, dpart, M_ROWS, 64, D_INNER / 4, D_INNER, D_INNER);
        reduce_dbc_k<<<M_ROWS * 64 / 256, 256, 0, stream>>>(dpart, dbc, dltb);

        // dltS(bf16) = softplus(delta @ dt_w^T + dt_b)
        gemm_bf16<64, 64, true, false, 1, true><<<dim3(D_INNER / 64, M_ROWS / 64), 256, 0, stream>>>(
            dltb, dtwb, dt_b + (size_t)i * D_INNER, dltS, M_ROWS, D_INNER, DT_RANK, DT_RANK, DT_RANK);

        scan1_k<<<BB * NCHUNK * (D_INNER / 64), 256, 0, stream>>>(
            dltS, xsb, dbc, A_log + (size_t)i * D_INNER * D_STATE, cbuf);
        scan2_k<<<BB * NCHUNK * (D_INNER / 64), 256, 0, stream>>>(
            dltS, xsb, dbc, xrb, A_log + (size_t)i * D_INNER * D_STATE,
            Dp + (size_t)i * D_INNER, cbuf, xyb);

        // h += y @ out_w^T   (m97 structure, BN=64, XCD swizzle)
        gemm_gl<64, 8, D_MODEL, D_INNER, false, true, false>
            <<<dim3(8, M_ROWS / 128), 256, 0, stream>>>(xyb, owb, nullptr, h);
    }

    rmsnorm_k<false><<<M_ROWS, 256, 0, stream>>>(h, final_norm_w, fnorm, nullptr);
    stats1_k<<<BB * 16, D_MODEL, 0, stream>>>(fnorm, dpart);
    stats2_k<<<BB, D_MODEL, 0, stream>>>(dpart, (float*)d_out);
}